// Round 3
// baseline (214.925 us; speedup 1.0000x reference)
//
#include <hip/hip_runtime.h>

// MoE GLU MLP: E=8, D=1024, H=1024, K=2, N=2048 tokens, 4096 pairs.
// R10: corrected ds_read_b64_tr_b16 usage based on the surviving semantics model:
//   per-lane 8B read at its own address; per 16-lane group the 128B (row j =
//   lanes 4j..4j+3) is transposed 4x16 -> lane p gets column p, elems j=0..3.
// Weight tiles staged in NATURAL [k][n] layout (n-contiguous) via global_load_lds;
// lane (q, r=lane&15) addresses row q*8+pr*4+(r>>2), n-chunk (r&3)*4 -> fragment
// B[k=q*8+pr*4+j][col=lane&15]. 16B-unit XOR swizzle (both-sides: inverse-permuted
// global source + same XOR in tr-read addr) gives conflict-free (4-cycle floor) reads.
// Prep: pure streaming fp32->bf16 cvt (no LDS bounce); out-zero in prep; W2-cvt
// streams in gemm1's aux z-slice.

typedef __bf16 bf16x8 __attribute__((ext_vector_type(8)));
typedef __bf16 bf16x4 __attribute__((ext_vector_type(4)));
typedef float  f32x4  __attribute__((ext_vector_type(4)));
typedef unsigned int u32x2 __attribute__((ext_vector_type(2)));

#define NPAIR 4096
#define NTOK  2048
#define DDIM  1024
#define HDIM  1024
#define NEXP  8

// workspace layout (bytes)
#define ORDER_I   64                      // int index of order[] in wsi
#define XB_OFF    (24576)                 // bf16 x     [2048][1024]       4 MB
#define W1B_OFF   (XB_OFF + 4194304)      // bf16 W1 [8][1024][2048] nat. 32 MB
#define W2B_OFF   (W1B_OFF + 33554432)    // bf16 W2 [8][1024][1024] nat. 16 MB
#define ACT_OFF   (W2B_OFF + 16777216)    // bf16 act   [5120][1024]    10.5 MB

#define GLOAD_LDS16(g, l) \
    __builtin_amdgcn_global_load_lds( \
        (const __attribute__((address_space(1))) void*)(g), \
        (__attribute__((address_space(3))) void*)(l), 16, 0, 0)

#define LDS_OFF(p) ((unsigned int)(unsigned long long)(__attribute__((address_space(3))) void*)(p))

// streaming fp32 -> bf16, 8 elems (16B load x2, 16B store)
__device__ __forceinline__ void cvt8(const float* __restrict__ s, __bf16* __restrict__ d) {
    float4 v0 = *(const float4*)s;
    float4 v1 = *(const float4*)(s + 4);
    bf16x8 o;
    o[0] = (__bf16)v0.x; o[1] = (__bf16)v0.y; o[2] = (__bf16)v0.z; o[3] = (__bf16)v0.w;
    o[4] = (__bf16)v1.x; o[5] = (__bf16)v1.y; o[6] = (__bf16)v1.z; o[7] = (__bf16)v1.w;
    *(bf16x8*)d = o;
}

// ---------------- prep: W1-cvt (2048) + x-cvt (512) + out-zero (512) + bucket (8) ----------------
__global__ __launch_bounds__(256) void prep_kernel(const float* __restrict__ x,
                                                   const float* __restrict__ W1,
                                                   const int* __restrict__ idx,
                                                   int* __restrict__ wsi,
                                                   __bf16* __restrict__ xb,
                                                   __bf16* __restrict__ w1b,
                                                   float* __restrict__ out) {
    __shared__ int cnt[NEXP];
    __shared__ int sbase, scur;
    const int b = blockIdx.x;
    const int tid = threadIdx.x;
    if (b < 2048) {
        size_t base = (size_t)b * 8192 + tid * 8;
#pragma unroll
        for (int j = 0; j < 4; j++)
            cvt8(W1 + base + j * 2048, w1b + base + j * 2048);
    } else if (b < 2560) {
        size_t base = (size_t)(b - 2048) * 4096 + tid * 8;
#pragma unroll
        for (int j = 0; j < 2; j++)
            cvt8(x + base + j * 2048, xb + base + j * 2048);
    } else if (b < 3072) {
        float4 z4 = {0.f, 0.f, 0.f, 0.f};
        size_t base = (size_t)(b - 2560) * 4096 + tid * 4;
#pragma unroll
        for (int j = 0; j < 4; j++)
            *(float4*)(out + base + j * 1024) = z4;
    } else {
        const int e = b - 3072;
        if (tid < NEXP) cnt[tid] = 0;
        if (tid == 0) scur = 0;
        __syncthreads();
        for (int i = tid; i < NPAIR; i += 256) atomicAdd(&cnt[idx[i] & 7], 1);
        __syncthreads();
        if (tid == 0) {
            int off = 0;
            for (int e2 = 0; e2 < NEXP; e2++) {
                if (e2 == e) { wsi[e] = cnt[e]; wsi[8 + e] = off; sbase = off; }
                off += (cnt[e2] + 127) & ~127;
            }
        }
        __syncthreads();
        for (int i = tid; i < NPAIR; i += 256) {
            if ((idx[i] & 7) == e) {
                int s = atomicAdd(&scur, 1);
                wsi[ORDER_I + sbase + s] = i;
            }
        }
    }
}

// ---------------- gemm1: 64m x 64 out-cols (z<8) + aux W2-cvt (z==8) ----------------
__global__ __launch_bounds__(256) void gemm1_kernel(const __bf16* __restrict__ xb,
                                                    const __bf16* __restrict__ w1b,
                                                    const int* __restrict__ wsi,
                                                    __bf16* __restrict__ act,
                                                    const float* __restrict__ W2,
                                                    __bf16* __restrict__ w2b) {
    __shared__ __align__(16) char smem[24576];   // As 8K | Bs 16K ([64 k][128 n] nat, swizzled)
    const int tid = threadIdx.x;
    const int z = blockIdx.z;

    if (z >= 8) {                                // 1024 aux blocks: streaming W2 cvt
        int aux = blockIdx.y * 16 + blockIdx.x;
        size_t base = (size_t)aux * 8192 + tid * 8;
#pragma unroll
        for (int j = 0; j < 4; j++)
            cvt8(W2 + base + j * 2048, w2b + base + j * 2048);
        return;
    }

    const int e = z;
    const int cnt = wsi[e];
    const int m0 = blockIdx.y * 64;
    if (m0 >= cnt) return;
    const int base = wsi[8 + e];
    const int n0 = blockIdx.x * 64;
    const int* order = wsi + ORDER_I;
    const __bf16* w1e = w1b + (size_t)e * 2048 * 1024;   // natural [k=1024][col=2048]

    __bf16 (*As)[64] = (__bf16 (*)[64])smem;
    __bf16* Bs = (__bf16*)(smem + 8192);                 // [64][128] bf16, 16B-unit swizzled

    const int lane = tid & 63, w = tid >> 6;
    const int lm = lane & 15, q = lane >> 4;
    const int wm = w & 1, wn = w >> 1;                   // 2 m-waves x 2 n-waves
    const int x7 = lm & 7;
    const int sw0 = (q ^ x7) * 16;
    const int sw1 = ((4 + q) ^ x7) * 16;

    // A source: XOR-swizzled global addrs (baseline, proven)
    const __bf16* ga[2];
#pragma unroll
    for (int j = 0; j < 2; j++) {
        int c = j * 256 + tid;
        int r2 = c >> 3;
        int ks = ((c & 7) ^ (r2 & 7)) * 8;
        int m = m0 + r2; if (m >= cnt) m = cnt - 1;
        int tok = order[base + m] >> 1;
        ga[j] = xb + (size_t)tok * DDIM + ks;
    }
    // B source: slot c -> LDS bytes c*16 = (k = c>>4, phys unit = c&15).
    // logical unit ul = up ^ ((k&7)<<1); ul covers B-tile cols [ul*8, ul*8+8),
    // mapped to W1 col via h/g interleave (bt = ul*8.. : h64 = ul>>3, rr = (ul&7)*8).
    const __bf16* gb[4];
#pragma unroll
    for (int j = 0; j < 4; j++) {
        int c = j * 256 + tid;
        int k = c >> 4;
        int ul = (c & 15) ^ ((k & 7) << 1);
        int u7 = ul & 7, h64 = ul >> 3;
        int colW = (u7 < 4) ? (n0 + h64 * 32 + u7 * 8)
                            : (HDIM + n0 + h64 * 32 + (u7 - 4) * 8);
        gb[j] = w1e + (size_t)k * 2048 + colW;
    }

    // tr-read per-lane addresses, per (nt, pr); kh via +8192 immediate.
    const int r = lm;
    unsigned int trb[4][2];
#pragma unroll
    for (int nt = 0; nt < 4; nt++)
#pragma unroll
        for (int pr = 0; pr < 2; pr++) {
            int row = q * 8 + pr * 4 + (r >> 2);
            int ul = wn * 8 + nt * 2 + ((r & 3) >> 1);
            int up = ul ^ (((pr * 4 + (r >> 2)) & 7) << 1);
            trb[nt][pr] = LDS_OFF(Bs) + row * 256 + up * 16 + (r & 1) * 8;
        }

    f32x4 acc[2][4];
#pragma unroll
    for (int mt = 0; mt < 2; mt++)
#pragma unroll
        for (int nt = 0; nt < 4; nt++) acc[mt][nt] = (f32x4){0.f, 0.f, 0.f, 0.f};

    for (int k0 = 0; k0 < DDIM; k0 += 64) {
        __syncthreads();
#pragma unroll
        for (int j = 0; j < 2; j++) {
            GLOAD_LDS16(ga[j], (char*)smem + (j * 256 + tid) * 16);
            ga[j] += 64;
        }
#pragma unroll
        for (int j = 0; j < 4; j++) {
            GLOAD_LDS16(gb[j], (char*)Bs + (j * 256 + tid) * 16);
            gb[j] += 64 * 2048;
        }
        __syncthreads();
#pragma unroll
        for (int kh = 0; kh < 2; kh++) {
            const int sw = kh ? sw1 : sw0;
            bf16x8 af[2];
#pragma unroll
            for (int mt = 0; mt < 2; mt++)
                af[mt] = *(const bf16x8*)((const char*)&As[wm * 32 + mt * 16 + lm][0] + sw);
            u32x2 t0[4], t1[4];
#pragma unroll
            for (int nt = 0; nt < 4; nt++) {
                asm volatile("ds_read_b64_tr_b16 %0, %1 offset:%c2"
                             : "=&v"(t0[nt]) : "v"(trb[nt][0]), "i"(kh * 8192));
                asm volatile("ds_read_b64_tr_b16 %0, %1 offset:%c2"
                             : "=&v"(t1[nt]) : "v"(trb[nt][1]), "i"(kh * 8192));
            }
            asm volatile("s_waitcnt lgkmcnt(0)" ::: "memory");
            __builtin_amdgcn_sched_barrier(0);
#pragma unroll
            for (int nt = 0; nt < 4; nt++) {
                union { unsigned int u[4]; bf16x8 v; } bb;
                bb.u[0] = t0[nt][0]; bb.u[1] = t0[nt][1];
                bb.u[2] = t1[nt][0]; bb.u[3] = t1[nt][1];
#pragma unroll
                for (int mt = 0; mt < 2; mt++)
                    acc[mt][nt] = __builtin_amdgcn_mfma_f32_16x16x32_bf16(af[mt], bb.v, acc[mt][nt], 0, 0, 0);
            }
        }
    }

#pragma unroll
    for (int mt = 0; mt < 2; mt++) {
        int mbase = m0 + wm * 32 + mt * 16 + q * 4;
#pragma unroll
        for (int ntp = 0; ntp < 2; ntp++) {
            int col = n0 + wn * 32 + ntp * 16 + lm;
#pragma unroll
            for (int rr = 0; rr < 4; rr++) {
                int m = mbase + rr;
                if (m < cnt) {
                    float h = acc[mt][ntp][rr];
                    float g = acc[mt][ntp + 2][rr];
                    float a = h * (g / (1.f + __expf(-g)));
                    act[(size_t)(base + m) * HDIM + col] = (__bf16)a;
                }
            }
        }
    }
}

// ---------------- gemm2: 64m x 64n, fused p-weighted atomic combine ----------------
__global__ __launch_bounds__(256) void gemm2_kernel(const __bf16* __restrict__ act,
                                                    const __bf16* __restrict__ w2b,
                                                    const int* __restrict__ wsi,
                                                    const float* __restrict__ p,
                                                    float* __restrict__ out) {
    const int e = blockIdx.z;
    const int cnt = wsi[e];
    const int m0 = blockIdx.y * 64;
    if (m0 >= cnt) return;
    const int base = wsi[8 + e];
    const int n0 = blockIdx.x * 64;
    const int* order = wsi + ORDER_I;
    const __bf16* w2e = w2b + (size_t)e * 1024 * 1024;   // natural [k=1024][n=1024]

    __shared__ __align__(16) char smem[16384];           // As 8K | Bs 8K ([64 k][64 n] nat, swizzled)
    __bf16 (*As)[64] = (__bf16 (*)[64])smem;
    __bf16* Bs = (__bf16*)(smem + 8192);

    const int tid = threadIdx.x;
    const int lane = tid & 63, w = tid >> 6;
    const int lm = lane & 15, q = lane >> 4;
    const int wm = w & 1, wn = w >> 1;
    const int x7 = lm & 7;
    const int sw0 = (q ^ x7) * 16;
    const int sw1 = ((4 + q) ^ x7) * 16;

    const __bf16* ga[2];
#pragma unroll
    for (int j = 0; j < 2; j++) {
        int c = j * 256 + tid;
        int r2 = c >> 3;
        int ks = ((c & 7) ^ (r2 & 7)) * 8;
        ga[j] = act + (size_t)(base + m0 + r2) * HDIM + ks;   // pad rows masked at epilogue
    }
    // B source: slot c -> (k = c>>3, phys unit c&7); logical unit = up ^ ((k&3)<<1)
    const __bf16* gb[2];
#pragma unroll
    for (int j = 0; j < 2; j++) {
        int c = j * 256 + tid;
        int k = c >> 3;
        int ul = (c & 7) ^ ((k & 3) << 1);
        gb[j] = w2e + (size_t)k * 1024 + n0 + ul * 8;
    }

    const int r = lm;
    unsigned int trb[2];
#pragma unroll
    for (int nt = 0; nt < 2; nt++) {
        int row = q * 8 + (r >> 2);
        int ul = wn * 4 + nt * 2 + ((r & 3) >> 1);
        int up = ul ^ (((r >> 2) & 3) << 1);
        trb[nt] = LDS_OFF(Bs) + row * 128 + up * 16 + (r & 1) * 8;
    }

    f32x4 acc[2][2];
#pragma unroll
    for (int mt = 0; mt < 2; mt++)
#pragma unroll
        for (int nt = 0; nt < 2; nt++) acc[mt][nt] = (f32x4){0.f, 0.f, 0.f, 0.f};

    for (int k0 = 0; k0 < HDIM; k0 += 64) {
        __syncthreads();
#pragma unroll
        for (int j = 0; j < 2; j++) {
            GLOAD_LDS16(ga[j], (char*)smem + (j * 256 + tid) * 16);
            GLOAD_LDS16(gb[j], (char*)Bs + (j * 256 + tid) * 16);
            ga[j] += 64; gb[j] += 64 * 1024;
        }
        __syncthreads();
#pragma unroll
        for (int kh = 0; kh < 2; kh++) {
            const int sw = kh ? sw1 : sw0;
            bf16x8 af[2];
#pragma unroll
            for (int mt = 0; mt < 2; mt++)
                af[mt] = *(const bf16x8*)((const char*)&As[wm * 32 + mt * 16 + lm][0] + sw);
            u32x2 t0[2], t1[2];
#pragma unroll
            for (int nt = 0; nt < 2; nt++) {
                asm volatile("ds_read_b64_tr_b16 %0, %1 offset:%c2"
                             : "=&v"(t0[nt]) : "v"(trb[nt]), "i"(kh * 4096));
                asm volatile("ds_read_b64_tr_b16 %0, %1 offset:%c2"
                             : "=&v"(t1[nt]) : "v"(trb[nt]), "i"(kh * 4096 + 512));
            }
            asm volatile("s_waitcnt lgkmcnt(0)" ::: "memory");
            __builtin_amdgcn_sched_barrier(0);
#pragma unroll
            for (int nt = 0; nt < 2; nt++) {
                union { unsigned int u[4]; bf16x8 v; } bb;
                bb.u[0] = t0[nt][0]; bb.u[1] = t0[nt][1];
                bb.u[2] = t1[nt][0]; bb.u[3] = t1[nt][1];
#pragma unroll
                for (int mt = 0; mt < 2; mt++)
                    acc[mt][nt] = __builtin_amdgcn_mfma_f32_16x16x32_bf16(af[mt], bb.v, acc[mt][nt], 0, 0, 0);
            }
        }
    }

    int pi[2][4];
    float pw[2][4];
#pragma unroll
    for (int mt = 0; mt < 2; mt++)
#pragma unroll
        for (int rr = 0; rr < 4; rr++) {
            int gm = m0 + wm * 32 + mt * 16 + q * 4 + rr;
            if (gm < cnt) {
                int pr = order[base + gm];
                pi[mt][rr] = pr;
                pw[mt][rr] = p[pr];
            } else pi[mt][rr] = -1;
        }
#pragma unroll
    for (int mt = 0; mt < 2; mt++)
#pragma unroll
        for (int nt = 0; nt < 2; nt++) {
            int col = n0 + wn * 32 + nt * 16 + lm;
#pragma unroll
            for (int rr = 0; rr < 4; rr++) {
                if (pi[mt][rr] >= 0) {
                    int tok = pi[mt][rr] >> 1;
                    atomicAdd(out + (size_t)tok * DDIM + col, pw[mt][rr] * acc[mt][nt][rr]);
                }
            }
        }
}

extern "C" void kernel_launch(void* const* d_in, const int* in_sizes, int n_in,
                              void* d_out, int out_size, void* d_ws, size_t ws_size,
                              hipStream_t stream) {
    (void)in_sizes; (void)n_in; (void)out_size; (void)ws_size;
    const float* x   = (const float*)d_in[0];
    const float* p   = (const float*)d_in[1];
    const int* eidx  = (const int*)d_in[2];
    const float* W1  = (const float*)d_in[3];
    const float* W2  = (const float*)d_in[4];
    float* out = (float*)d_out;

    char* ws = (char*)d_ws;
    int* wsi     = (int*)ws;
    __bf16* xb   = (__bf16*)(ws + XB_OFF);
    __bf16* w1b  = (__bf16*)(ws + W1B_OFF);
    __bf16* w2b  = (__bf16*)(ws + W2B_OFF);
    __bf16* act  = (__bf16*)(ws + ACT_OFF);

    prep_kernel<<<3080, 256, 0, stream>>>(x, W1, eidx, wsi, xb, w1b, out);
    // z<8: gemm1 (64m tiles); z==8: 1024 streaming W2-cvt blocks
    gemm1_kernel<<<dim3(16, 64, 9), 256, 0, stream>>>(xb, w1b, wsi, act, W2, w2b);
    gemm2_kernel<<<dim3(16, 64, NEXP), 256, 0, stream>>>(act, w2b, wsi, p, out);
}

// Round 4
// 206.608 us; speedup vs baseline: 1.0403x; 1.0403x over previous
//
#include <hip/hip_runtime.h>

// MoE GLU MLP: E=8, D=1024, H=1024, K=2, N=2048 tokens, 4096 pairs.
// R11 = R7 baseline (proven 203.8us: bounce-transposed bf16 weights, XOR-swizzled
// ds_read_b128 fragments, 64x64 tiles) + minimum 2-phase prefetch pipeline (T3
// recipe, m248v2) in both GEMMs:
//   - double-buffered LDS (gemm1 2x24KB, gemm2 2x16KB)
//   - issue next tile's global_load_lds BEFORE computing current tile
//   - raw s_barrier + manual s_waitcnt vmcnt(0) at END of iteration (prefetch
//     latency hides under ds_read+MFMA; avoids __syncthreads' full pre-compute drain)
//   - T5 setprio(1) around MFMA clusters.

typedef __bf16 bf16x8 __attribute__((ext_vector_type(8)));
typedef __bf16 bf16x4 __attribute__((ext_vector_type(4)));
typedef float  f32x4  __attribute__((ext_vector_type(4)));

#define NPAIR 4096
#define NTOK  2048
#define DDIM  1024
#define HDIM  1024
#define NEXP  8

// workspace layout (bytes)
#define ORDER_I   64                      // int index of order[] in wsi
#define XB_OFF    (24576)                 // bf16 x        [2048][1024]   4 MB
#define W1T_OFF   (XB_OFF + 4194304)      // bf16 W1^T  [8][2048][1024]  32 MB
#define W2T_OFF   (W1T_OFF + 33554432)    // bf16 W2^T  [8][1024][1024]  16 MB
#define ACT_OFF   (W2T_OFF + 16777216)    // bf16 act      [5120][1024] 10.5 MB

#define GLOAD_LDS16(g, l) \
    __builtin_amdgcn_global_load_lds( \
        (const __attribute__((address_space(1))) void*)(g), \
        (__attribute__((address_space(3))) void*)(l), 16, 0, 0)

// 64k x 64n transpose-convert tile: fp32 LDS bounce, float4 loads, bf16x8 stores
__device__ __forceinline__ void tcvt64(const float* __restrict__ s,
                                       __bf16* __restrict__ d,
                                       int R, int C, int k0, int c0,
                                       float (*tt)[65], int tid) {
#pragma unroll
    for (int p = 0; p < 4; p++) {
        int kr = p * 16 + (tid >> 4);
        int nc = (tid & 15) * 4;
        *(float4*)&tt[kr][nc] = *(const float4*)(s + (size_t)(k0 + kr) * C + c0 + nc);
    }
    __syncthreads();
#pragma unroll
    for (int p = 0; p < 2; p++) {
        int cid = p * 256 + tid;
        int n = cid >> 3, kc = cid & 7;
        bf16x8 o;
#pragma unroll
        for (int j = 0; j < 8; j++) o[j] = (__bf16)tt[kc * 8 + j][n];
        *(bf16x8*)(d + (size_t)(c0 + n) * R + k0 + kc * 8) = o;
    }
}

// ---------------- prep: W1-cvt (4096) + x-cvt (2048) + bucket (8) ----------------
__global__ __launch_bounds__(256) void prep_kernel(const float* __restrict__ x,
                                                   const float* __restrict__ W1,
                                                   const int* __restrict__ idx,
                                                   int* __restrict__ wsi,
                                                   __bf16* __restrict__ xb,
                                                   __bf16* __restrict__ w1t) {
    __shared__ float tt[64][65];
    __shared__ int cnt[NEXP];
    __shared__ int sbase, scur;
    const int b = blockIdx.x;
    const int tid = threadIdx.x;
    if (b < 4096) {
        int e = b >> 9, t2 = b & 511;
        int k0 = (t2 & 15) * 64, c0 = (t2 >> 4) * 64;
        tcvt64(W1 + (size_t)e * DDIM * 2 * HDIM, w1t + (size_t)e * 2 * HDIM * DDIM,
               DDIM, 2 * HDIM, k0, c0, tt, tid);
    } else if (b < 6144) {
        int i = (b - 4096) * 1024 + tid * 4;
        float4 v = *(const float4*)(x + i);
        bf16x4 o;
        o[0] = (__bf16)v.x; o[1] = (__bf16)v.y; o[2] = (__bf16)v.z; o[3] = (__bf16)v.w;
        *(bf16x4*)(xb + i) = o;
    } else {
        const int e = b - 6144;
        if (tid < NEXP) cnt[tid] = 0;
        if (tid == 0) scur = 0;
        __syncthreads();
        for (int i = tid; i < NPAIR; i += 256) atomicAdd(&cnt[idx[i] & 7], 1);
        __syncthreads();
        if (tid == 0) {
            int off = 0;
            for (int e2 = 0; e2 < NEXP; e2++) {
                if (e2 == e) { wsi[e] = cnt[e]; wsi[8 + e] = off; sbase = off; }
                off += (cnt[e2] + 127) & ~127;
            }
        }
        __syncthreads();
        for (int i = tid; i < NPAIR; i += 256) {
            if ((idx[i] & 7) == e) {
                int s = atomicAdd(&scur, 1);
                wsi[ORDER_I + sbase + s] = i;
            }
        }
    }
}

// ---------------- gemm1: 64m x 64 out-cols (z<8) + aux (z>=8) ----------------
__global__ __launch_bounds__(256) void gemm1_kernel(const __bf16* __restrict__ xb,
                                                    const __bf16* __restrict__ w1t,
                                                    const int* __restrict__ wsi,
                                                    __bf16* __restrict__ act,
                                                    const float* __restrict__ W2,
                                                    __bf16* __restrict__ w2t,
                                                    float* __restrict__ out) {
    __shared__ __align__(16) char smem[49152];   // 2 x (As 8K | Bs 16K); aux: fp32 [64][65]
    const int tid = threadIdx.x;
    const int z = blockIdx.z;

    if (z >= 8) {
        int aux = (z - 8) * 1024 + blockIdx.y * 16 + blockIdx.x;
        if (aux < 2048) {
            int e = aux >> 8, t2 = aux & 255;
            int k0 = (t2 & 15) * 64, c0 = (t2 >> 4) * 64;
            tcvt64(W2 + (size_t)e * HDIM * DDIM, w2t + (size_t)e * DDIM * HDIM,
                   HDIM, DDIM, k0, c0, (float (*)[65])smem, tid);
        } else if (aux < 2560) {
            int zb = aux - 2048;                 // 512 blocks zero 8 MB
            float4 z4 = {0.f, 0.f, 0.f, 0.f};
            int b4 = zb * 4096;
#pragma unroll
            for (int j = 0; j < 4; j++)
                *(float4*)(out + b4 + j * 1024 + tid * 4) = z4;
        }
        return;
    }

    const int e = z;
    const int cnt = wsi[e];
    const int m0 = blockIdx.y * 64;
    if (m0 >= cnt) return;
    const int base = wsi[8 + e];
    const int n0 = blockIdx.x * 64;
    const int* order = wsi + ORDER_I;
    const __bf16* w1e = w1t + (size_t)e * 2048 * 1024;

    const int lane = tid & 63, w = tid >> 6;
    const int lm = lane & 15, q = lane >> 4;
    const int wm = w & 1, wn = w >> 1;
    const int x7 = lm & 7;
    const int sw0 = (q ^ x7) * 16;
    const int sw1 = ((4 + q) ^ x7) * 16;

    const __bf16* ga[2];
    const __bf16* gb[4];
#pragma unroll
    for (int j = 0; j < 2; j++) {
        int c = j * 256 + tid;
        int r = c >> 3;
        int ks = ((c & 7) ^ (r & 7)) * 8;
        int m = m0 + r; if (m >= cnt) m = cnt - 1;
        int tok = order[base + m] >> 1;
        ga[j] = xb + (size_t)tok * DDIM + ks;
    }
#pragma unroll
    for (int j = 0; j < 4; j++) {
        int c = j * 256 + tid;
        int r = c >> 3;
        int ks = ((c & 7) ^ (r & 7)) * 8;
        int half = r >> 6, rr = r & 63;
        int rb = (rr < 32) ? (n0 + half * 32 + rr)
                           : (HDIM + n0 + half * 32 + (rr - 32));
        gb[j] = w1e + (size_t)rb * DDIM + ks;
    }

    f32x4 acc[2][4];
#pragma unroll
    for (int mt = 0; mt < 2; mt++)
#pragma unroll
        for (int nt = 0; nt < 4; nt++) acc[mt][nt] = (f32x4){0.f, 0.f, 0.f, 0.f};

    // ---- prologue: stage tile 0 into buf0, drain, barrier ----
#pragma unroll
    for (int j = 0; j < 2; j++) {
        GLOAD_LDS16(ga[j], smem + (j * 256 + tid) * 16);
        ga[j] += 64;
    }
#pragma unroll
    for (int j = 0; j < 4; j++) {
        GLOAD_LDS16(gb[j], smem + 8192 + (j * 256 + tid) * 16);
        gb[j] += 64;
    }
    asm volatile("s_waitcnt vmcnt(0)" ::: "memory");
    __builtin_amdgcn_s_barrier();

    // ---- 2-phase main loop: prefetch t+1, compute t, drain+barrier ----
    for (int t = 0; t < 16; ++t) {
        char* cbase = smem + (t & 1) * 24576;
        if (t < 15) {
            char* nbase = smem + ((t & 1) ^ 1) * 24576;
#pragma unroll
            for (int j = 0; j < 2; j++) {
                GLOAD_LDS16(ga[j], nbase + (j * 256 + tid) * 16);
                ga[j] += 64;
            }
#pragma unroll
            for (int j = 0; j < 4; j++) {
                GLOAD_LDS16(gb[j], nbase + 8192 + (j * 256 + tid) * 16);
                gb[j] += 64;
            }
        }
        __builtin_amdgcn_sched_barrier(0);   // pin prefetch issue before compute
        __bf16 (*As)[64] = (__bf16 (*)[64])cbase;
        __bf16 (*Bs)[64] = (__bf16 (*)[64])(cbase + 8192);
#pragma unroll
        for (int kh = 0; kh < 2; kh++) {
            const int sw = kh ? sw1 : sw0;
            bf16x8 af[2];
#pragma unroll
            for (int mt = 0; mt < 2; mt++)
                af[mt] = *(const bf16x8*)((const char*)&As[wm * 32 + mt * 16 + lm][0] + sw);
            __builtin_amdgcn_s_setprio(1);
#pragma unroll
            for (int nt = 0; nt < 4; nt++) {
                bf16x8 bfr = *(const bf16x8*)((const char*)&Bs[wn * 64 + nt * 16 + lm][0] + sw);
#pragma unroll
                for (int mt = 0; mt < 2; mt++)
                    acc[mt][nt] = __builtin_amdgcn_mfma_f32_16x16x32_bf16(af[mt], bfr, acc[mt][nt], 0, 0, 0);
            }
            __builtin_amdgcn_s_setprio(0);
        }
        asm volatile("s_waitcnt vmcnt(0)" ::: "memory");
        __builtin_amdgcn_s_barrier();
    }

#pragma unroll
    for (int mt = 0; mt < 2; mt++) {
        int mbase = m0 + wm * 32 + mt * 16 + q * 4;
#pragma unroll
        for (int ntp = 0; ntp < 2; ntp++) {
            int col = n0 + wn * 32 + ntp * 16 + lm;
#pragma unroll
            for (int r = 0; r < 4; r++) {
                int m = mbase + r;
                if (m < cnt) {
                    float h = acc[mt][ntp][r];
                    float g = acc[mt][ntp + 2][r];
                    float a = h * (g / (1.f + __expf(-g)));
                    act[(size_t)(base + m) * HDIM + col] = (__bf16)a;
                }
            }
        }
    }
}

// ---------------- gemm2: 64m x 64n, fused p-weighted atomic combine ----------------
__global__ __launch_bounds__(256) void gemm2_kernel(const __bf16* __restrict__ act,
                                                    const __bf16* __restrict__ w2t,
                                                    const int* __restrict__ wsi,
                                                    const float* __restrict__ p,
                                                    float* __restrict__ out) {
    const int e = blockIdx.z;
    const int cnt = wsi[e];
    const int m0 = blockIdx.y * 64;
    if (m0 >= cnt) return;
    const int base = wsi[8 + e];
    const int n0 = blockIdx.x * 64;
    const int* order = wsi + ORDER_I;
    const __bf16* w2e = w2t + (size_t)e * 1024 * 1024;

    __shared__ __align__(16) char smem[32768];   // 2 x (As 8K | Bs 8K)

    const int tid = threadIdx.x;
    const int lane = tid & 63, w = tid >> 6;
    const int lm = lane & 15, q = lane >> 4;
    const int wm = w & 1, wn = w >> 1;
    const int x7 = lm & 7;
    const int sw0 = (q ^ x7) * 16;
    const int sw1 = ((4 + q) ^ x7) * 16;

    const __bf16* ga[2];
    const __bf16* gb[2];
#pragma unroll
    for (int j = 0; j < 2; j++) {
        int c = j * 256 + tid;
        int r = c >> 3;
        int ks = ((c & 7) ^ (r & 7)) * 8;
        ga[j] = act + (size_t)(base + m0 + r) * HDIM + ks;   // pad rows masked at epilogue
        gb[j] = w2e + (size_t)(n0 + r) * HDIM + ks;
    }

    f32x4 acc[2][2];
#pragma unroll
    for (int mt = 0; mt < 2; mt++)
#pragma unroll
        for (int nt = 0; nt < 2; nt++) acc[mt][nt] = (f32x4){0.f, 0.f, 0.f, 0.f};

    // ---- prologue ----
#pragma unroll
    for (int j = 0; j < 2; j++) {
        GLOAD_LDS16(ga[j], smem + (j * 256 + tid) * 16);
        GLOAD_LDS16(gb[j], smem + 8192 + (j * 256 + tid) * 16);
        ga[j] += 64; gb[j] += 64;
    }
    asm volatile("s_waitcnt vmcnt(0)" ::: "memory");
    __builtin_amdgcn_s_barrier();

    // ---- 2-phase main loop ----
    for (int t = 0; t < 16; ++t) {
        char* cbase = smem + (t & 1) * 16384;
        if (t < 15) {
            char* nbase = smem + ((t & 1) ^ 1) * 16384;
#pragma unroll
            for (int j = 0; j < 2; j++) {
                GLOAD_LDS16(ga[j], nbase + (j * 256 + tid) * 16);
                GLOAD_LDS16(gb[j], nbase + 8192 + (j * 256 + tid) * 16);
                ga[j] += 64; gb[j] += 64;
            }
        }
        __builtin_amdgcn_sched_barrier(0);
        __bf16 (*As)[64] = (__bf16 (*)[64])cbase;
        __bf16 (*Bs)[64] = (__bf16 (*)[64])(cbase + 8192);
#pragma unroll
        for (int kh = 0; kh < 2; kh++) {
            const int sw = kh ? sw1 : sw0;
            bf16x8 af[2];
#pragma unroll
            for (int mt = 0; mt < 2; mt++)
                af[mt] = *(const bf16x8*)((const char*)&As[wm * 32 + mt * 16 + lm][0] + sw);
            __builtin_amdgcn_s_setprio(1);
#pragma unroll
            for (int nt = 0; nt < 2; nt++) {
                bf16x8 bfr = *(const bf16x8*)((const char*)&Bs[wn * 32 + nt * 16 + lm][0] + sw);
#pragma unroll
                for (int mt = 0; mt < 2; mt++)
                    acc[mt][nt] = __builtin_amdgcn_mfma_f32_16x16x32_bf16(af[mt], bfr, acc[mt][nt], 0, 0, 0);
            }
            __builtin_amdgcn_s_setprio(0);
        }
        asm volatile("s_waitcnt vmcnt(0)" ::: "memory");
        __builtin_amdgcn_s_barrier();
    }

    int pi[2][4];
    float pw[2][4];
#pragma unroll
    for (int mt = 0; mt < 2; mt++)
#pragma unroll
        for (int r = 0; r < 4; r++) {
            int gm = m0 + wm * 32 + mt * 16 + q * 4 + r;
            if (gm < cnt) {
                int pr = order[base + gm];
                pi[mt][r] = pr;
                pw[mt][r] = p[pr];
            } else pi[mt][r] = -1;
        }
#pragma unroll
    for (int mt = 0; mt < 2; mt++)
#pragma unroll
        for (int nt = 0; nt < 2; nt++) {
            int col = n0 + wn * 32 + nt * 16 + lm;
#pragma unroll
            for (int r = 0; r < 4; r++) {
                if (pi[mt][r] >= 0) {
                    int tok = pi[mt][r] >> 1;
                    atomicAdd(out + (size_t)tok * DDIM + col, pw[mt][r] * acc[mt][nt][r]);
                }
            }
        }
}

extern "C" void kernel_launch(void* const* d_in, const int* in_sizes, int n_in,
                              void* d_out, int out_size, void* d_ws, size_t ws_size,
                              hipStream_t stream) {
    (void)in_sizes; (void)n_in; (void)out_size; (void)ws_size;
    const float* x   = (const float*)d_in[0];
    const float* p   = (const float*)d_in[1];
    const int* eidx  = (const int*)d_in[2];
    const float* W1  = (const float*)d_in[3];
    const float* W2  = (const float*)d_in[4];
    float* out = (float*)d_out;

    char* ws = (char*)d_ws;
    int* wsi     = (int*)ws;
    __bf16* xb   = (__bf16*)(ws + XB_OFF);
    __bf16* w1t  = (__bf16*)(ws + W1T_OFF);
    __bf16* w2t  = (__bf16*)(ws + W2T_OFF);
    __bf16* act  = (__bf16*)(ws + ACT_OFF);

    prep_kernel<<<6152, 256, 0, stream>>>(x, W1, eidx, wsi, xb, w1t);
    // z<8: gemm1 (64m tiles); z in [8,11): 2048 W2-cvt tiles + 512 out-zero blocks
    gemm1_kernel<<<dim3(16, 64, 11), 256, 0, stream>>>(xb, w1t, wsi, act, W2, w2t, out);
    gemm2_kernel<<<dim3(16, 64, NEXP), 256, 0, stream>>>(act, w2t, wsi, p, out);
}

// Round 5
// 200.485 us; speedup vs baseline: 1.0720x; 1.0305x over previous
//
#include <hip/hip_runtime.h>

// MoE GLU MLP: E=8, D=1024, H=1024, K=2, N=2048 tokens, 4096 pairs.
// R12 = R11 with the 2-phase pipeline converted from drain-to-0 to COUNTED vmcnt
// (m218: counted-vs-drain0 is the entire gain of the pipeline):
//   loop t: issue tile t+1 loads -> s_waitcnt vmcnt(LOADS_IN_FLIGHT) -> barrier
//           -> compute tile t -> barrier.
// Tile t+1's global_load_lds stay outstanding across both barriers and compute.
// gemm1: 6 loads/tile -> vmcnt(6);  gemm2: 4 loads/tile -> vmcnt(4).
// Everything else identical to R11 (proven-correct staging/swizzle/epilogues).

typedef __bf16 bf16x8 __attribute__((ext_vector_type(8)));
typedef __bf16 bf16x4 __attribute__((ext_vector_type(4)));
typedef float  f32x4  __attribute__((ext_vector_type(4)));

#define NPAIR 4096
#define NTOK  2048
#define DDIM  1024
#define HDIM  1024
#define NEXP  8

// workspace layout (bytes)
#define ORDER_I   64                      // int index of order[] in wsi
#define XB_OFF    (24576)                 // bf16 x        [2048][1024]   4 MB
#define W1T_OFF   (XB_OFF + 4194304)      // bf16 W1^T  [8][2048][1024]  32 MB
#define W2T_OFF   (W1T_OFF + 33554432)    // bf16 W2^T  [8][1024][1024]  16 MB
#define ACT_OFF   (W2T_OFF + 16777216)    // bf16 act      [5120][1024] 10.5 MB

#define GLOAD_LDS16(g, l) \
    __builtin_amdgcn_global_load_lds( \
        (const __attribute__((address_space(1))) void*)(g), \
        (__attribute__((address_space(3))) void*)(l), 16, 0, 0)

// 64k x 64n transpose-convert tile: fp32 LDS bounce, float4 loads, bf16x8 stores
__device__ __forceinline__ void tcvt64(const float* __restrict__ s,
                                       __bf16* __restrict__ d,
                                       int R, int C, int k0, int c0,
                                       float (*tt)[65], int tid) {
#pragma unroll
    for (int p = 0; p < 4; p++) {
        int kr = p * 16 + (tid >> 4);
        int nc = (tid & 15) * 4;
        *(float4*)&tt[kr][nc] = *(const float4*)(s + (size_t)(k0 + kr) * C + c0 + nc);
    }
    __syncthreads();
#pragma unroll
    for (int p = 0; p < 2; p++) {
        int cid = p * 256 + tid;
        int n = cid >> 3, kc = cid & 7;
        bf16x8 o;
#pragma unroll
        for (int j = 0; j < 8; j++) o[j] = (__bf16)tt[kc * 8 + j][n];
        *(bf16x8*)(d + (size_t)(c0 + n) * R + k0 + kc * 8) = o;
    }
}

// ---------------- prep: W1-cvt (4096) + x-cvt (2048) + bucket (8) ----------------
__global__ __launch_bounds__(256) void prep_kernel(const float* __restrict__ x,
                                                   const float* __restrict__ W1,
                                                   const int* __restrict__ idx,
                                                   int* __restrict__ wsi,
                                                   __bf16* __restrict__ xb,
                                                   __bf16* __restrict__ w1t) {
    __shared__ float tt[64][65];
    __shared__ int cnt[NEXP];
    __shared__ int sbase, scur;
    const int b = blockIdx.x;
    const int tid = threadIdx.x;
    if (b < 4096) {
        int e = b >> 9, t2 = b & 511;
        int k0 = (t2 & 15) * 64, c0 = (t2 >> 4) * 64;
        tcvt64(W1 + (size_t)e * DDIM * 2 * HDIM, w1t + (size_t)e * 2 * HDIM * DDIM,
               DDIM, 2 * HDIM, k0, c0, tt, tid);
    } else if (b < 6144) {
        int i = (b - 4096) * 1024 + tid * 4;
        float4 v = *(const float4*)(x + i);
        bf16x4 o;
        o[0] = (__bf16)v.x; o[1] = (__bf16)v.y; o[2] = (__bf16)v.z; o[3] = (__bf16)v.w;
        *(bf16x4*)(xb + i) = o;
    } else {
        const int e = b - 6144;
        if (tid < NEXP) cnt[tid] = 0;
        if (tid == 0) scur = 0;
        __syncthreads();
        for (int i = tid; i < NPAIR; i += 256) atomicAdd(&cnt[idx[i] & 7], 1);
        __syncthreads();
        if (tid == 0) {
            int off = 0;
            for (int e2 = 0; e2 < NEXP; e2++) {
                if (e2 == e) { wsi[e] = cnt[e]; wsi[8 + e] = off; sbase = off; }
                off += (cnt[e2] + 127) & ~127;
            }
        }
        __syncthreads();
        for (int i = tid; i < NPAIR; i += 256) {
            if ((idx[i] & 7) == e) {
                int s = atomicAdd(&scur, 1);
                wsi[ORDER_I + sbase + s] = i;
            }
        }
    }
}

// ---------------- gemm1: 64m x 64 out-cols (z<8) + aux (z>=8) ----------------
__global__ __launch_bounds__(256) void gemm1_kernel(const __bf16* __restrict__ xb,
                                                    const __bf16* __restrict__ w1t,
                                                    const int* __restrict__ wsi,
                                                    __bf16* __restrict__ act,
                                                    const float* __restrict__ W2,
                                                    __bf16* __restrict__ w2t,
                                                    float* __restrict__ out) {
    __shared__ __align__(16) char smem[49152];   // 2 x (As 8K | Bs 16K); aux: fp32 [64][65]
    const int tid = threadIdx.x;
    const int z = blockIdx.z;

    if (z >= 8) {
        int aux = (z - 8) * 1024 + blockIdx.y * 16 + blockIdx.x;
        if (aux < 2048) {
            int e = aux >> 8, t2 = aux & 255;
            int k0 = (t2 & 15) * 64, c0 = (t2 >> 4) * 64;
            tcvt64(W2 + (size_t)e * HDIM * DDIM, w2t + (size_t)e * DDIM * HDIM,
                   HDIM, DDIM, k0, c0, (float (*)[65])smem, tid);
        } else if (aux < 2560) {
            int zb = aux - 2048;                 // 512 blocks zero 8 MB
            float4 z4 = {0.f, 0.f, 0.f, 0.f};
            int b4 = zb * 4096;
#pragma unroll
            for (int j = 0; j < 4; j++)
                *(float4*)(out + b4 + j * 1024 + tid * 4) = z4;
        }
        return;
    }

    const int e = z;
    const int cnt = wsi[e];
    const int m0 = blockIdx.y * 64;
    if (m0 >= cnt) return;
    const int base = wsi[8 + e];
    const int n0 = blockIdx.x * 64;
    const int* order = wsi + ORDER_I;
    const __bf16* w1e = w1t + (size_t)e * 2048 * 1024;

    const int lane = tid & 63, w = tid >> 6;
    const int lm = lane & 15, q = lane >> 4;
    const int wm = w & 1, wn = w >> 1;
    const int x7 = lm & 7;
    const int sw0 = (q ^ x7) * 16;
    const int sw1 = ((4 + q) ^ x7) * 16;

    const __bf16* ga[2];
    const __bf16* gb[4];
#pragma unroll
    for (int j = 0; j < 2; j++) {
        int c = j * 256 + tid;
        int r = c >> 3;
        int ks = ((c & 7) ^ (r & 7)) * 8;
        int m = m0 + r; if (m >= cnt) m = cnt - 1;
        int tok = order[base + m] >> 1;
        ga[j] = xb + (size_t)tok * DDIM + ks;
    }
#pragma unroll
    for (int j = 0; j < 4; j++) {
        int c = j * 256 + tid;
        int r = c >> 3;
        int ks = ((c & 7) ^ (r & 7)) * 8;
        int half = r >> 6, rr = r & 63;
        int rb = (rr < 32) ? (n0 + half * 32 + rr)
                           : (HDIM + n0 + half * 32 + (rr - 32));
        gb[j] = w1e + (size_t)rb * DDIM + ks;
    }

    f32x4 acc[2][4];
#pragma unroll
    for (int mt = 0; mt < 2; mt++)
#pragma unroll
        for (int nt = 0; nt < 4; nt++) acc[mt][nt] = (f32x4){0.f, 0.f, 0.f, 0.f};

    // ---- prologue: issue tile 0 into buf0 (no drain) ----
#pragma unroll
    for (int j = 0; j < 2; j++) {
        GLOAD_LDS16(ga[j], smem + (j * 256 + tid) * 16);
        ga[j] += 64;
    }
#pragma unroll
    for (int j = 0; j < 4; j++) {
        GLOAD_LDS16(gb[j], smem + 8192 + (j * 256 + tid) * 16);
        gb[j] += 64;
    }

    // ---- 2-phase main loop, counted vmcnt: tile t+1 stays in flight ----
    for (int t = 0; t < 16; ++t) {
        char* cbase = smem + (t & 1) * 24576;
        if (t < 15) {
            char* nbase = smem + ((t + 1) & 1) * 24576;
#pragma unroll
            for (int j = 0; j < 2; j++) {
                GLOAD_LDS16(ga[j], nbase + (j * 256 + tid) * 16);
                ga[j] += 64;
            }
#pragma unroll
            for (int j = 0; j < 4; j++) {
                GLOAD_LDS16(gb[j], nbase + 8192 + (j * 256 + tid) * 16);
                gb[j] += 64;
            }
            asm volatile("s_waitcnt vmcnt(6)" ::: "memory");   // tile t landed
        } else {
            asm volatile("s_waitcnt vmcnt(0)" ::: "memory");
        }
        __builtin_amdgcn_s_barrier();
        __builtin_amdgcn_sched_barrier(0);
        __bf16 (*As)[64] = (__bf16 (*)[64])cbase;
        __bf16 (*Bs)[64] = (__bf16 (*)[64])(cbase + 8192);
#pragma unroll
        for (int kh = 0; kh < 2; kh++) {
            const int sw = kh ? sw1 : sw0;
            bf16x8 af[2];
#pragma unroll
            for (int mt = 0; mt < 2; mt++)
                af[mt] = *(const bf16x8*)((const char*)&As[wm * 32 + mt * 16 + lm][0] + sw);
            __builtin_amdgcn_s_setprio(1);
#pragma unroll
            for (int nt = 0; nt < 4; nt++) {
                bf16x8 bfr = *(const bf16x8*)((const char*)&Bs[wn * 64 + nt * 16 + lm][0] + sw);
#pragma unroll
                for (int mt = 0; mt < 2; mt++)
                    acc[mt][nt] = __builtin_amdgcn_mfma_f32_16x16x32_bf16(af[mt], bfr, acc[mt][nt], 0, 0, 0);
            }
            __builtin_amdgcn_s_setprio(0);
        }
        __builtin_amdgcn_sched_barrier(0);
        __builtin_amdgcn_s_barrier();                // done reading buf[t&1]
    }

#pragma unroll
    for (int mt = 0; mt < 2; mt++) {
        int mbase = m0 + wm * 32 + mt * 16 + q * 4;
#pragma unroll
        for (int ntp = 0; ntp < 2; ntp++) {
            int col = n0 + wn * 32 + ntp * 16 + lm;
#pragma unroll
            for (int r = 0; r < 4; r++) {
                int m = mbase + r;
                if (m < cnt) {
                    float h = acc[mt][ntp][r];
                    float g = acc[mt][ntp + 2][r];
                    float a = h * (g / (1.f + __expf(-g)));
                    act[(size_t)(base + m) * HDIM + col] = (__bf16)a;
                }
            }
        }
    }
}

// ---------------- gemm2: 64m x 64n, fused p-weighted atomic combine ----------------
__global__ __launch_bounds__(256) void gemm2_kernel(const __bf16* __restrict__ act,
                                                    const __bf16* __restrict__ w2t,
                                                    const int* __restrict__ wsi,
                                                    const float* __restrict__ p,
                                                    float* __restrict__ out) {
    const int e = blockIdx.z;
    const int cnt = wsi[e];
    const int m0 = blockIdx.y * 64;
    if (m0 >= cnt) return;
    const int base = wsi[8 + e];
    const int n0 = blockIdx.x * 64;
    const int* order = wsi + ORDER_I;
    const __bf16* w2e = w2t + (size_t)e * 1024 * 1024;

    __shared__ __align__(16) char smem[32768];   // 2 x (As 8K | Bs 8K)

    const int tid = threadIdx.x;
    const int lane = tid & 63, w = tid >> 6;
    const int lm = lane & 15, q = lane >> 4;
    const int wm = w & 1, wn = w >> 1;
    const int x7 = lm & 7;
    const int sw0 = (q ^ x7) * 16;
    const int sw1 = ((4 + q) ^ x7) * 16;

    const __bf16* ga[2];
    const __bf16* gb[2];
#pragma unroll
    for (int j = 0; j < 2; j++) {
        int c = j * 256 + tid;
        int r = c >> 3;
        int ks = ((c & 7) ^ (r & 7)) * 8;
        ga[j] = act + (size_t)(base + m0 + r) * HDIM + ks;   // pad rows masked at epilogue
        gb[j] = w2e + (size_t)(n0 + r) * HDIM + ks;
    }

    f32x4 acc[2][2];
#pragma unroll
    for (int mt = 0; mt < 2; mt++)
#pragma unroll
        for (int nt = 0; nt < 2; nt++) acc[mt][nt] = (f32x4){0.f, 0.f, 0.f, 0.f};

    // ---- prologue: issue tile 0 (no drain) ----
#pragma unroll
    for (int j = 0; j < 2; j++) {
        GLOAD_LDS16(ga[j], smem + (j * 256 + tid) * 16);
        GLOAD_LDS16(gb[j], smem + 8192 + (j * 256 + tid) * 16);
        ga[j] += 64; gb[j] += 64;
    }

    // ---- 2-phase main loop, counted vmcnt ----
    for (int t = 0; t < 16; ++t) {
        char* cbase = smem + (t & 1) * 16384;
        if (t < 15) {
            char* nbase = smem + ((t + 1) & 1) * 16384;
#pragma unroll
            for (int j = 0; j < 2; j++) {
                GLOAD_LDS16(ga[j], nbase + (j * 256 + tid) * 16);
                GLOAD_LDS16(gb[j], nbase + 8192 + (j * 256 + tid) * 16);
                ga[j] += 64; gb[j] += 64;
            }
            asm volatile("s_waitcnt vmcnt(4)" ::: "memory");   // tile t landed
        } else {
            asm volatile("s_waitcnt vmcnt(0)" ::: "memory");
        }
        __builtin_amdgcn_s_barrier();
        __builtin_amdgcn_sched_barrier(0);
        __bf16 (*As)[64] = (__bf16 (*)[64])cbase;
        __bf16 (*Bs)[64] = (__bf16 (*)[64])(cbase + 8192);
#pragma unroll
        for (int kh = 0; kh < 2; kh++) {
            const int sw = kh ? sw1 : sw0;
            bf16x8 af[2];
#pragma unroll
            for (int mt = 0; mt < 2; mt++)
                af[mt] = *(const bf16x8*)((const char*)&As[wm * 32 + mt * 16 + lm][0] + sw);
            __builtin_amdgcn_s_setprio(1);
#pragma unroll
            for (int nt = 0; nt < 2; nt++) {
                bf16x8 bfr = *(const bf16x8*)((const char*)&Bs[wn * 32 + nt * 16 + lm][0] + sw);
#pragma unroll
                for (int mt = 0; mt < 2; mt++)
                    acc[mt][nt] = __builtin_amdgcn_mfma_f32_16x16x32_bf16(af[mt], bfr, acc[mt][nt], 0, 0, 0);
            }
            __builtin_amdgcn_s_setprio(0);
        }
        __builtin_amdgcn_sched_barrier(0);
        __builtin_amdgcn_s_barrier();                // done reading buf[t&1]
    }

    int pi[2][4];
    float pw[2][4];
#pragma unroll
    for (int mt = 0; mt < 2; mt++)
#pragma unroll
        for (int r = 0; r < 4; r++) {
            int gm = m0 + wm * 32 + mt * 16 + q * 4 + r;
            if (gm < cnt) {
                int pr = order[base + gm];
                pi[mt][r] = pr;
                pw[mt][r] = p[pr];
            } else pi[mt][r] = -1;
        }
#pragma unroll
    for (int mt = 0; mt < 2; mt++)
#pragma unroll
        for (int nt = 0; nt < 2; nt++) {
            int col = n0 + wn * 32 + nt * 16 + lm;
#pragma unroll
            for (int r = 0; r < 4; r++) {
                if (pi[mt][r] >= 0) {
                    int tok = pi[mt][r] >> 1;
                    atomicAdd(out + (size_t)tok * DDIM + col, pw[mt][r] * acc[mt][nt][r]);
                }
            }
        }
}

extern "C" void kernel_launch(void* const* d_in, const int* in_sizes, int n_in,
                              void* d_out, int out_size, void* d_ws, size_t ws_size,
                              hipStream_t stream) {
    (void)in_sizes; (void)n_in; (void)out_size; (void)ws_size;
    const float* x   = (const float*)d_in[0];
    const float* p   = (const float*)d_in[1];
    const int* eidx  = (const int*)d_in[2];
    const float* W1  = (const float*)d_in[3];
    const float* W2  = (const float*)d_in[4];
    float* out = (float*)d_out;

    char* ws = (char*)d_ws;
    int* wsi     = (int*)ws;
    __bf16* xb   = (__bf16*)(ws + XB_OFF);
    __bf16* w1t  = (__bf16*)(ws + W1T_OFF);
    __bf16* w2t  = (__bf16*)(ws + W2T_OFF);
    __bf16* act  = (__bf16*)(ws + ACT_OFF);

    prep_kernel<<<6152, 256, 0, stream>>>(x, W1, eidx, wsi, xb, w1t);
    // z<8: gemm1 (64m tiles); z in [8,11): 2048 W2-cvt tiles + 512 out-zero blocks
    gemm1_kernel<<<dim3(16, 64, 11), 256, 0, stream>>>(xb, w1t, wsi, act, W2, w2t, out);
    gemm2_kernel<<<dim3(16, 64, NEXP), 256, 0, stream>>>(act, w2t, wsi, p, out);
}